// Round 5
// baseline (10265.910 us; speedup 1.0000x reference)
//
#include <hip/hip_runtime.h>

typedef unsigned short u16;
typedef unsigned int   u32;
typedef unsigned long long u64;
typedef __attribute__((ext_vector_type(8))) __bf16 bf16x8;
typedef __attribute__((ext_vector_type(4))) float   f32x4;

#define B_   64
#define H_   1024
#define E_   512
#define G4_  4096
#define T_   1024
#define NWG  64      // recurrent workgroups (16 h-cols each)

// ---------- helpers ----------
__device__ __forceinline__ u16 f2b(float f){           // fp32 -> bf16 RNE
  union { float f; u32 u; } v; v.f = f;
  u32 r = v.u + 0x7fffu + ((v.u >> 16) & 1u);
  return (u16)(r >> 16);
}
__device__ __forceinline__ float b2f(u16 u){
  union { u32 u; float f; } v; v.u = ((u32)u) << 16;
  return v.f;
}
__device__ __forceinline__ float sigf(float x){
  return 1.0f / (1.0f + __expf(-x));
}
__device__ __forceinline__ float tanhf_s(float x){     // overflow-safe tanh
  float ax = fabsf(x);
  float e  = __expf(2.0f * ax);
  float t  = 1.0f - 2.0f / (e + 1.0f);
  return copysignf(t, x);
}
__device__ __forceinline__ void gload_lds16(const void* g, void* l){
  __builtin_amdgcn_global_load_lds(
      (const __attribute__((address_space(1))) u32*)g,
      (__attribute__((address_space(3))) u32*)l, 16, 0, 0);
}

// ---------- prep: fp32 -> bf16 (Wx only) ----------
__global__ __launch_bounds__(256) void cvt_bf16(const float* __restrict__ in,
                                                u16* __restrict__ out, int n){
  int i = (blockIdx.x * 256 + threadIdx.x) * 4;
  if (i >= n) return;
  float4 v = *reinterpret_cast<const float4*>(in + i);
  ushort4 o;
  o.x = f2b(v.x); o.y = f2b(v.y); o.z = f2b(v.z); o.w = f2b(v.w);
  *reinterpret_cast<ushort4*>(out + i) = o;
}

// ---------- per-segment: embSeg[ts*64+b][e] = bf16(emb[src[b][t0+ts]][e]) ----------
__global__ __launch_bounds__(256) void emb_gather(const int* __restrict__ src,
                                                  const float* __restrict__ emb,
                                                  u16* __restrict__ embSeg, int t0){
  int idx = blockIdx.x * 256 + threadIdx.x;
  int m  = idx >> 7;
  int e4 = (idx & 127) << 2;
  int b = m & 63, ts = m >> 6;
  int tok = src[b * T_ + t0 + ts];
  float4 v = *reinterpret_cast<const float4*>(emb + (size_t)tok * E_ + e4);
  ushort4 o;
  o.x = f2b(v.x); o.y = f2b(v.y); o.z = f2b(v.z); o.w = f2b(v.w);
  *reinterpret_cast<ushort4*>(embSeg + (size_t)m * E_ + e4) = o;
}

// ---------- per-segment GEMM: xp[m][g] = sum_e embSeg[m][e]*Wx[g][e] + bx[g] ----------
__global__ __launch_bounds__(256) void xproj_gemm(const u16* __restrict__ embSeg,
                                                  const u16* __restrict__ WxB,
                                                  const float* __restrict__ bx,
                                                  u16* __restrict__ xp){
  __shared__ alignas(16) u16 Al[2][128][64];
  __shared__ alignas(16) u16 Bl[2][128][64];
  const int tid  = threadIdx.x;
  const int lane = tid & 63, wv = tid >> 6;
  const int wm = wv >> 1, wn = wv & 1;
  const int m0 = blockIdx.y * 128, n0 = blockIdx.x * 128;

  const int srow_w = wv * 8 + (lane >> 3);
  const int csrc   = (lane & 7) ^ (lane >> 3);

  auto stage = [&](int buf, int kb){
    const int kbase = kb * 64 + csrc * 8;
    #pragma unroll
    for (int it = 0; it < 4; ++it){
      const u16* ga = embSeg + (size_t)(m0 + it * 32 + srow_w) * E_ + kbase;
      gload_lds16(ga, &Al[buf][it * 32 + wv * 8][0]);
    }
    #pragma unroll
    for (int it = 0; it < 4; ++it){
      const u16* gb = WxB + (size_t)(n0 + it * 32 + srow_w) * E_ + kbase;
      gload_lds16(gb, &Bl[buf][it * 32 + wv * 8][0]);
    }
  };

  f32x4 acc[4][4] = {};
  stage(0, 0);
  __syncthreads();
  for (int kb = 0; kb < 8; ++kb){
    const int cur = kb & 1;
    if (kb < 7) stage(cur ^ 1, kb + 1);
    #pragma unroll
    for (int kk = 0; kk < 2; ++kk){
      bf16x8 af[4], bfr[4];
      #pragma unroll
      for (int i = 0; i < 4; ++i){
        int row = wm * 64 + i * 16 + (lane & 15);
        int cp  = (kk * 4 + (lane >> 4)) ^ (row & 7);
        af[i] = *reinterpret_cast<const bf16x8*>(&Al[cur][row][cp * 8]);
      }
      #pragma unroll
      for (int j = 0; j < 4; ++j){
        int row = wn * 64 + j * 16 + (lane & 15);
        int cp  = (kk * 4 + (lane >> 4)) ^ (row & 7);
        bfr[j] = *reinterpret_cast<const bf16x8*>(&Bl[cur][row][cp * 8]);
      }
      #pragma unroll
      for (int i = 0; i < 4; ++i)
        #pragma unroll
        for (int j = 0; j < 4; ++j)
          acc[i][j] = __builtin_amdgcn_mfma_f32_16x16x32_bf16(af[i], bfr[j], acc[i][j], 0, 0, 0);
    }
    __syncthreads();
  }

  float bxv[4];
  #pragma unroll
  for (int j = 0; j < 4; ++j) bxv[j] = bx[n0 + wn * 64 + j * 16 + (lane & 15)];
  #pragma unroll
  for (int i = 0; i < 4; ++i){
    int mrow = m0 + wm * 64 + i * 16 + ((lane >> 4) << 2);
    #pragma unroll
    for (int r = 0; r < 4; ++r){
      size_t base = (size_t)(mrow + r) * G4_ + n0 + wn * 64 + (lane & 15);
      #pragma unroll
      for (int j = 0; j < 4; ++j)
        xp[base + j * 16] = f2b(acc[i][j][r] + bxv[j]);
    }
  }
}

// ---------- recurrent kernel over steps [t0, t1) ----------
// 64 WGs x 256 threads (4 waves). WG wg owns h-cols [wg*16, wg*16+16), all 4 gates.
// Sync: ZERO atomics, ZERO barriers in the loop. Each wave, after its h(t) sc1-stores
// drain (vmcnt 0), sc1-stores flags[t][wg*4+wv]=1 (plain store, no RMW -> no line
// locking). Consumers poll all 256 flags read-only (2 u64 sc1 loads/lane + __all),
// then read the ring slot with normal cached dwordx4 loads (first touch of that slot
// this dispatch is post-publish -> L2 cold-miss fetches fresh LLC data, 8 WGs/XCD share).
__global__ __launch_bounds__(256, 1) void lstm_rec(const float* __restrict__ Wh,
                                                   const u16* __restrict__ xp,
                                                   u16* __restrict__ hring,     // [SEG][64][1024] bf16
                                                   float* __restrict__ c_state, // [64][1024]
                                                   u32* __restrict__ flags,     // [T_][256] zeroed once
                                                   float* __restrict__ out,
                                                   int t0, int t1, int segm1){
  __shared__ alignas(16) u16 Wl[64][1024];          // 128 KB
  const int tid  = threadIdx.x;
  const int lane = tid & 63, wv = tid >> 6;
  const int wg   = blockIdx.x;

  // stage Wh slice once, fp32 -> bf16 in-register.
  // Swizzle: LDS 16B-chunk c of row r holds global K-chunk c ^ (r & 15)
  // (16-slot / 256 B window -> a wave's 16 rows land 2-way per bank pair = free; the
  //  old (r&7) 128 B window forced 4-way = ~500 stall-cy/wave/step, 8.3M/dispatch).
  for (int it = tid; it < 64 * 128; it += 256){
    int r = it >> 7, c = it & 127;
    int gc = c ^ (r & 15);
    const float* gsrc = Wh + ((size_t)(r >> 4) * H_ + wg * 16 + (r & 15)) * H_ + gc * 8;
    float4 a = *reinterpret_cast<const float4*>(gsrc);
    float4 d = *reinterpret_cast<const float4*>(gsrc + 4);
    union { u16 s[8]; uint4 q; } u;
    u.s[0]=f2b(a.x); u.s[1]=f2b(a.y); u.s[2]=f2b(a.z); u.s[3]=f2b(a.w);
    u.s[4]=f2b(d.x); u.s[5]=f2b(d.y); u.s[6]=f2b(d.z); u.s[7]=f2b(d.w);
    *reinterpret_cast<uint4*>(&Wl[r][c * 8]) = u.q;
  }
  __syncthreads();

  const int b     = wv * 16 + (lane & 15);          // batch row (C col) this lane owns
  const int jbase = (lane >> 4) << 2;               // j base for the 4 acc regs
  const u64 ONE2  = 0x0000000100000001ULL;

  float cst[4];
  if (t0 == 0){
    cst[0] = cst[1] = cst[2] = cst[3] = 0.f;
  } else {
    float4 cv = *reinterpret_cast<const float4*>(c_state + (size_t)b * H_ + wg * 16 + jbase);
    cst[0] = cv.x; cst[1] = cv.y; cst[2] = cv.z; cst[3] = cv.w;
  }

  for (int t = t0; t < t1; ++t){
    const int ts = t - t0;
    // xp prefetch (cached; independent of h) — overlaps the flag wait
    ushort4 xv[4];
    const u16* xrow = xp + ((size_t)ts * B_ + b) * G4_ + wg * 16 + jbase;
    #pragma unroll
    for (int q = 0; q < 4; ++q)
      xv[q] = *reinterpret_cast<const ushort4*>(xrow + q * H_);

    f32x4 acc[4] = {};
    if (t > 0){
      // ---- poll: 256 per-wave flags, read-only, 2 u64 per lane ----
      const u64* fl = (const u64*)(flags + (size_t)(t - 1) * 256) + lane * 2;
      for (;;){
        u64 a  = __hip_atomic_load(fl,     __ATOMIC_RELAXED, __HIP_MEMORY_SCOPE_AGENT);
        u64 b2 = __hip_atomic_load(fl + 1, __ATOMIC_RELAXED, __HIP_MEMORY_SCOPE_AGENT);
        if (__all(a == ONE2 && b2 == ONE2)) break;
      }
      asm volatile("" ::: "memory");                 // no load hoisting above the poll

      // ---- cached, coalesced h loads from the cold ring slot ----
      const u16* hp = hring + (size_t)((t - 1) & segm1) * (B_ * H_)
                    + (size_t)b * H_ + ((lane >> 4) << 3);
      uint4 hq[32];
      #pragma unroll
      for (int ks = 0; ks < 32; ++ks)
        hq[ks] = *reinterpret_cast<const uint4*>(hp + ks * 32);

      // 8 independent accumulation chains (accA: ks 0..15, accB: ks 16..31)
      f32x4 accA[4] = {}, accB[4] = {};
      #pragma unroll
      for (int ks = 0; ks < 16; ++ks){
        union { uint4 q; bf16x8 v; } u; u.q = hq[ks];
        #pragma unroll
        for (int m = 0; m < 4; ++m){
          int row = m * 16 + (lane & 15);
          int cp2 = (ks * 4 + (lane >> 4)) ^ (row & 15);
          bf16x8 aw = *reinterpret_cast<const bf16x8*>(&Wl[row][cp2 * 8]);
          accA[m] = __builtin_amdgcn_mfma_f32_16x16x32_bf16(aw, u.v, accA[m], 0, 0, 0);
        }
      }
      #pragma unroll
      for (int ks = 16; ks < 32; ++ks){
        union { uint4 q; bf16x8 v; } u; u.q = hq[ks];
        #pragma unroll
        for (int m = 0; m < 4; ++m){
          int row = m * 16 + (lane & 15);
          int cp2 = (ks * 4 + (lane >> 4)) ^ (row & 15);
          bf16x8 aw = *reinterpret_cast<const bf16x8*>(&Wl[row][cp2 * 8]);
          accB[m] = __builtin_amdgcn_mfma_f32_16x16x32_bf16(aw, u.v, accB[m], 0, 0, 0);
        }
      }
      #pragma unroll
      for (int m = 0; m < 4; ++m) acc[m] = accA[m] + accB[m];
    }

    // epilogue: lane holds i,f,o,g for (b, j=jbase+r), r=0..3
    float hv[4];
    #pragma unroll
    for (int r = 0; r < 4; ++r){
      u16 x0 = (r==0)?xv[0].x:(r==1)?xv[0].y:(r==2)?xv[0].z:xv[0].w;
      u16 x1 = (r==0)?xv[1].x:(r==1)?xv[1].y:(r==2)?xv[1].z:xv[1].w;
      u16 x2 = (r==0)?xv[2].x:(r==1)?xv[2].y:(r==2)?xv[2].z:xv[2].w;
      u16 x3 = (r==0)?xv[3].x:(r==1)?xv[3].y:(r==2)?xv[3].z:xv[3].w;
      float gi = sigf(acc[0][r] + b2f(x0));
      float gf = sigf(acc[1][r] + b2f(x1));
      float go = sigf(acc[2][r] + b2f(x2));
      float gg = tanhf_s(acc[3][r] + b2f(x3));
      cst[r] = (t == 0) ? gi * gg : gf * cst[r] + gi * gg;
      hv[r]  = go * tanhf_s(cst[r]);
    }

    if (t < T_ - 1){
      u64 pk =  (u64)f2b(hv[0])
             | ((u64)f2b(hv[1]) << 16)
             | ((u64)f2b(hv[2]) << 32)
             | ((u64)f2b(hv[3]) << 48);
      u64* hd = (u64*)(hring + (size_t)(t & segm1) * (B_ * H_)
                       + (size_t)b * H_ + wg * 16 + jbase);
      __hip_atomic_store(hd, pk, __ATOMIC_RELAXED, __HIP_MEMORY_SCOPE_AGENT);
      asm volatile("s_waitcnt vmcnt(0)" ::: "memory");   // this wave's h at LLC
      if (lane == 0)
        __hip_atomic_store(flags + (size_t)t * 256 + wg * 4 + wv, 1u,
                           __ATOMIC_RELAXED, __HIP_MEMORY_SCOPE_AGENT);
    } else {
      float4 ho; ho.x = hv[0]; ho.y = hv[1]; ho.z = hv[2]; ho.w = hv[3];
      float4 co; co.x = cst[0]; co.y = cst[1]; co.z = cst[2]; co.w = cst[3];
      *reinterpret_cast<float4*>(out + (size_t)b * H_ + wg * 16 + jbase) = ho;
      *reinterpret_cast<float4*>(out + (size_t)(B_ * H_) + (size_t)b * H_ + wg * 16 + jbase) = co;
    }
  }

  if (t1 < T_){
    float4 cv; cv.x = cst[0]; cv.y = cst[1]; cv.z = cst[2]; cv.w = cst[3];
    *reinterpret_cast<float4*>(c_state + (size_t)b * H_ + wg * 16 + jbase) = cv;
  }
}

// ---------- launch ----------
extern "C" void kernel_launch(void* const* d_in, const int* in_sizes, int n_in,
                              void* d_out, int out_size, void* d_ws, size_t ws_size,
                              hipStream_t stream){
  const int*   src = (const int*)  d_in[0];
  const float* emb = (const float*)d_in[1];
  const float* Wx  = (const float*)d_in[2];
  const float* bx  = (const float*)d_in[3];
  const float* Wh  = (const float*)d_in[4];

  // ws: WxB(4MB) | embSeg(SEG*64KB) | xpSeg(SEG*512KB) | hring(SEG*128KB) | c_state(256KB) | flags(1MB)
  const size_t FIXED  = 4194304 + 262144 + 1048576;      // 5,505,024
  const size_t PERSEG = 65536 + 524288 + 131072;         // 720,896
  int SEG = 64;
  if (ws_size < FIXED + 64 * PERSEG){
    if      (ws_size >= FIXED + 16 * PERSEG) SEG = 16;
    else if (ws_size >= FIXED + 4  * PERSEG) SEG = 4;
    else                                     SEG = 2;
  }

  char*  ws      = (char*)d_ws;
  u16*   WxB     = (u16*)(ws);
  u16*   embSeg  = (u16*)(ws + 4194304);
  u16*   xpSeg   = (u16*)(ws + 4194304 + (size_t)SEG * 65536);
  u16*   hring   = (u16*)(ws + 4194304 + (size_t)SEG * 589824);
  float* c_state = (float*)(ws + 4194304 + (size_t)SEG * 720896);
  u32*   flags   = (u32*) (ws + 4194304 + (size_t)SEG * 720896 + 262144);

  hipMemsetAsync(flags, 0, (size_t)T_ * 256 * 4, stream);
  cvt_bf16<<<2048, 256, 0, stream>>>(Wx, WxB, G4_ * E_);

  const int nseg = T_ / SEG;
  for (int s = 0; s < nseg; ++s){
    const int t0   = s * SEG;
    const int rows = SEG * B_;
    emb_gather<<<rows / 2, 256, 0, stream>>>(src, emb, embSeg, t0);
    dim3 g(G4_ / 128, rows / 128);
    xproj_gemm<<<g, 256, 0, stream>>>(embSeg, WxB, bx, xpSeg);
    lstm_rec<<<NWG, 256, 0, stream>>>(Wh, xpSeg, hring, c_state, flags,
                                      (float*)d_out, t0, t0 + SEG, SEG - 1);
  }
}

// Round 7
// 7090.863 us; speedup vs baseline: 1.4478x; 1.4478x over previous
//
#include <hip/hip_runtime.h>

typedef unsigned short u16;
typedef unsigned int   u32;
typedef unsigned long long u64;
typedef __attribute__((ext_vector_type(8))) __bf16 bf16x8;
typedef __attribute__((ext_vector_type(4))) float   f32x4;

#define B_   64
#define H_   1024
#define E_   512
#define G4_  4096
#define T_   1024
#define NWG  64      // recurrent workgroups (16 h-cols each)

// ---------- helpers ----------
__device__ __forceinline__ u16 f2b(float f){           // fp32 -> bf16 RNE
  union { float f; u32 u; } v; v.f = f;
  u32 r = v.u + 0x7fffu + ((v.u >> 16) & 1u);
  return (u16)(r >> 16);
}
__device__ __forceinline__ float b2f(u16 u){
  union { u32 u; float f; } v; v.u = ((u32)u) << 16;
  return v.f;
}
__device__ __forceinline__ float sigf(float x){
  return 1.0f / (1.0f + __expf(-x));
}
__device__ __forceinline__ float tanhf_s(float x){     // overflow-safe tanh
  float ax = fabsf(x);
  float e  = __expf(2.0f * ax);
  float t  = 1.0f - 2.0f / (e + 1.0f);
  return copysignf(t, x);
}
__device__ __forceinline__ void gload_lds16(const void* g, void* l){
  __builtin_amdgcn_global_load_lds(
      (const __attribute__((address_space(1))) u32*)g,
      (__attribute__((address_space(3))) u32*)l, 16, 0, 0);
}

// ---------- prep: fp32 -> bf16 (Wx only) ----------
__global__ __launch_bounds__(256) void cvt_bf16(const float* __restrict__ in,
                                                u16* __restrict__ out, int n){
  int i = (blockIdx.x * 256 + threadIdx.x) * 4;
  if (i >= n) return;
  float4 v = *reinterpret_cast<const float4*>(in + i);
  ushort4 o;
  o.x = f2b(v.x); o.y = f2b(v.y); o.z = f2b(v.z); o.w = f2b(v.w);
  *reinterpret_cast<ushort4*>(out + i) = o;
}

// ---------- per-segment: embSeg[ts*64+b][e] = bf16(emb[src[b][t0+ts]][e]) ----------
__global__ __launch_bounds__(256) void emb_gather(const int* __restrict__ src,
                                                  const float* __restrict__ emb,
                                                  u16* __restrict__ embSeg, int t0){
  int idx = blockIdx.x * 256 + threadIdx.x;
  int m  = idx >> 7;
  int e4 = (idx & 127) << 2;
  int b = m & 63, ts = m >> 6;
  int tok = src[b * T_ + t0 + ts];
  float4 v = *reinterpret_cast<const float4*>(emb + (size_t)tok * E_ + e4);
  ushort4 o;
  o.x = f2b(v.x); o.y = f2b(v.y); o.z = f2b(v.z); o.w = f2b(v.w);
  *reinterpret_cast<ushort4*>(embSeg + (size_t)m * E_ + e4) = o;
}

// ---------- per-segment GEMM: xp[m][g] = sum_e embSeg[m][e]*Wx[g][e] + bx[g] ----------
__global__ __launch_bounds__(256) void xproj_gemm(const u16* __restrict__ embSeg,
                                                  const u16* __restrict__ WxB,
                                                  const float* __restrict__ bx,
                                                  u16* __restrict__ xp){
  __shared__ alignas(16) u16 Al[2][128][64];
  __shared__ alignas(16) u16 Bl[2][128][64];
  const int tid  = threadIdx.x;
  const int lane = tid & 63, wv = tid >> 6;
  const int wm = wv >> 1, wn = wv & 1;
  const int m0 = blockIdx.y * 128, n0 = blockIdx.x * 128;

  const int srow_w = wv * 8 + (lane >> 3);
  const int csrc   = (lane & 7) ^ (lane >> 3);

  auto stage = [&](int buf, int kb){
    const int kbase = kb * 64 + csrc * 8;
    #pragma unroll
    for (int it = 0; it < 4; ++it){
      const u16* ga = embSeg + (size_t)(m0 + it * 32 + srow_w) * E_ + kbase;
      gload_lds16(ga, &Al[buf][it * 32 + wv * 8][0]);
    }
    #pragma unroll
    for (int it = 0; it < 4; ++it){
      const u16* gb = WxB + (size_t)(n0 + it * 32 + srow_w) * E_ + kbase;
      gload_lds16(gb, &Bl[buf][it * 32 + wv * 8][0]);
    }
  };

  f32x4 acc[4][4] = {};
  stage(0, 0);
  __syncthreads();
  for (int kb = 0; kb < 8; ++kb){
    const int cur = kb & 1;
    if (kb < 7) stage(cur ^ 1, kb + 1);
    #pragma unroll
    for (int kk = 0; kk < 2; ++kk){
      bf16x8 af[4], bfr[4];
      #pragma unroll
      for (int i = 0; i < 4; ++i){
        int row = wm * 64 + i * 16 + (lane & 15);
        int cp  = (kk * 4 + (lane >> 4)) ^ (row & 7);
        af[i] = *reinterpret_cast<const bf16x8*>(&Al[cur][row][cp * 8]);
      }
      #pragma unroll
      for (int j = 0; j < 4; ++j){
        int row = wn * 64 + j * 16 + (lane & 15);
        int cp  = (kk * 4 + (lane >> 4)) ^ (row & 7);
        bfr[j] = *reinterpret_cast<const bf16x8*>(&Bl[cur][row][cp * 8]);
      }
      #pragma unroll
      for (int i = 0; i < 4; ++i)
        #pragma unroll
        for (int j = 0; j < 4; ++j)
          acc[i][j] = __builtin_amdgcn_mfma_f32_16x16x32_bf16(af[i], bfr[j], acc[i][j], 0, 0, 0);
    }
    __syncthreads();
  }

  float bxv[4];
  #pragma unroll
  for (int j = 0; j < 4; ++j) bxv[j] = bx[n0 + wn * 64 + j * 16 + (lane & 15)];
  #pragma unroll
  for (int i = 0; i < 4; ++i){
    int mrow = m0 + wm * 64 + i * 16 + ((lane >> 4) << 2);
    #pragma unroll
    for (int r = 0; r < 4; ++r){
      size_t base = (size_t)(mrow + r) * G4_ + n0 + wn * 64 + (lane & 15);
      #pragma unroll
      for (int j = 0; j < 4; ++j)
        xp[base + j * 16] = f2b(acc[i][j][r] + bxv[j]);
    }
  }
}

// ---------- recurrent kernel over steps [t0, t1) ----------
// 64 WGs x 256 threads (4 waves). WG wg owns h-cols [wg*16, wg*16+16), all 4 gates.
// h transport: sc1 stores into ring slot (t & segm1) -> LLC; consumers read the slot
// with normal cached dwordx4 loads (first touch post-publish -> fresh from LLC, then
// 8 WGs/XCD share the L2 copy). Publish/poll via 8 TREE COUNTERS per step, each on
// its own 64B line: counter i <- atomicAdd by WGs [8i,8i+8) (RMW depth 8, 8 lines in
// parallel -- vs round 4's 64-deep single-line RMW under 256-wave read contention).
// Poll: lane spins on counter (lane&7): 8 distinct addrs/wave -> <=8 merged reqs/iter.
__global__ __launch_bounds__(256, 1) void lstm_rec(const float* __restrict__ Wh,
                                                   const u16* __restrict__ xp,
                                                   u16* __restrict__ hring,     // [SEG][64][1024] bf16
                                                   float* __restrict__ c_state, // [64][1024]
                                                   u32* __restrict__ cnt,       // [T_][8 x 64B] zeroed
                                                   float* __restrict__ out,
                                                   int t0, int t1, int segm1){
  __shared__ alignas(16) u16 Wl[64][1024];          // 128 KB
  const int tid  = threadIdx.x;
  const int lane = tid & 63, wv = tid >> 6;
  const int wg   = blockIdx.x;

  // stage Wh slice once, fp32 -> bf16 in-register.
  // Swizzle: LDS 16B-chunk c of row r holds global K-chunk c ^ (r & 15)
  // (16-slot/256B window -> wave's 16 rows are 2-way per bank pair = free; proven
  //  r5: BANK_CONFLICT 8.3M -> 33K).
  for (int it = tid; it < 64 * 128; it += 256){
    int r = it >> 7, c = it & 127;
    int gc = c ^ (r & 15);
    const float* gsrc = Wh + ((size_t)(r >> 4) * H_ + wg * 16 + (r & 15)) * H_ + gc * 8;
    float4 a = *reinterpret_cast<const float4*>(gsrc);
    float4 d = *reinterpret_cast<const float4*>(gsrc + 4);
    union { u16 s[8]; uint4 q; } u;
    u.s[0]=f2b(a.x); u.s[1]=f2b(a.y); u.s[2]=f2b(a.z); u.s[3]=f2b(a.w);
    u.s[4]=f2b(d.x); u.s[5]=f2b(d.y); u.s[6]=f2b(d.z); u.s[7]=f2b(d.w);
    *reinterpret_cast<uint4*>(&Wl[r][c * 8]) = u.q;
  }
  __syncthreads();

  const int b     = wv * 16 + (lane & 15);          // batch row (C col) this lane owns
  const int jbase = (lane >> 4) << 2;               // j base for the 4 acc regs

  float cst[4];
  if (t0 == 0){
    cst[0] = cst[1] = cst[2] = cst[3] = 0.f;
  } else {
    float4 cv = *reinterpret_cast<const float4*>(c_state + (size_t)b * H_ + wg * 16 + jbase);
    cst[0] = cv.x; cst[1] = cv.y; cst[2] = cv.z; cst[3] = cv.w;
  }

  for (int t = t0; t < t1; ++t){
    const int ts = t - t0;
    // xp prefetch (cached; independent of h) — overlaps the flag wait
    ushort4 xv[4];
    const u16* xrow = xp + ((size_t)ts * B_ + b) * G4_ + wg * 16 + jbase;
    #pragma unroll
    for (int q = 0; q < 4; ++q)
      xv[q] = *reinterpret_cast<const ushort4*>(xrow + q * H_);

    f32x4 acc[4] = {};
    if (t > 0){
      // ---- poll: lane spins on tree counter (lane&7); divergent exit == __all ----
      const u32* cp = cnt + ((size_t)(t - 1) * 8 + (lane & 7)) * 16;
      while (__hip_atomic_load(cp, __ATOMIC_RELAXED, __HIP_MEMORY_SCOPE_AGENT) < 8u) { }
      asm volatile("" ::: "memory");                 // no load hoisting above the poll

      // ---- cached, coalesced h loads from the cold ring slot ----
      const u16* hp = hring + (size_t)((t - 1) & segm1) * (B_ * H_)
                    + (size_t)b * H_ + ((lane >> 4) << 3);
      uint4 hq[32];
      #pragma unroll
      for (int ks = 0; ks < 32; ++ks)
        hq[ks] = *reinterpret_cast<const uint4*>(hp + ks * 32);

      // 8 independent accumulation chains (accA: ks 0..15, accB: ks 16..31)
      f32x4 accA[4] = {}, accB[4] = {};
      #pragma unroll
      for (int ks = 0; ks < 16; ++ks){
        union { uint4 q; bf16x8 v; } u; u.q = hq[ks];
        #pragma unroll
        for (int m = 0; m < 4; ++m){
          int row = m * 16 + (lane & 15);
          int cp2 = (ks * 4 + (lane >> 4)) ^ (row & 15);
          bf16x8 aw = *reinterpret_cast<const bf16x8*>(&Wl[row][cp2 * 8]);
          accA[m] = __builtin_amdgcn_mfma_f32_16x16x32_bf16(aw, u.v, accA[m], 0, 0, 0);
        }
      }
      #pragma unroll
      for (int ks = 16; ks < 32; ++ks){
        union { uint4 q; bf16x8 v; } u; u.q = hq[ks];
        #pragma unroll
        for (int m = 0; m < 4; ++m){
          int row = m * 16 + (lane & 15);
          int cp2 = (ks * 4 + (lane >> 4)) ^ (row & 15);
          bf16x8 aw = *reinterpret_cast<const bf16x8*>(&Wl[row][cp2 * 8]);
          accB[m] = __builtin_amdgcn_mfma_f32_16x16x32_bf16(aw, u.v, accB[m], 0, 0, 0);
        }
      }
      #pragma unroll
      for (int m = 0; m < 4; ++m) acc[m] = accA[m] + accB[m];
    }

    // epilogue: lane holds i,f,o,g for (b, j=jbase+r), r=0..3
    float hv[4];
    #pragma unroll
    for (int r = 0; r < 4; ++r){
      u16 x0 = (r==0)?xv[0].x:(r==1)?xv[0].y:(r==2)?xv[0].z:xv[0].w;
      u16 x1 = (r==0)?xv[1].x:(r==1)?xv[1].y:(r==2)?xv[1].z:xv[1].w;
      u16 x2 = (r==0)?xv[2].x:(r==1)?xv[2].y:(r==2)?xv[2].z:xv[2].w;
      u16 x3 = (r==0)?xv[3].x:(r==1)?xv[3].y:(r==2)?xv[3].z:xv[3].w;
      float gi = sigf(acc[0][r] + b2f(x0));
      float gf = sigf(acc[1][r] + b2f(x1));
      float go = sigf(acc[2][r] + b2f(x2));
      float gg = tanhf_s(acc[3][r] + b2f(x3));
      cst[r] = (t == 0) ? gi * gg : gf * cst[r] + gi * gg;
      hv[r]  = go * tanhf_s(cst[r]);
    }

    if (t < T_ - 1){
      u64 pk =  (u64)f2b(hv[0])
             | ((u64)f2b(hv[1]) << 16)
             | ((u64)f2b(hv[2]) << 32)
             | ((u64)f2b(hv[3]) << 48);
      u64* hd = (u64*)(hring + (size_t)(t & segm1) * (B_ * H_)
                       + (size_t)b * H_ + wg * 16 + jbase);
      __hip_atomic_store(hd, pk, __ATOMIC_RELAXED, __HIP_MEMORY_SCOPE_AGENT);
      asm volatile("s_waitcnt vmcnt(0)" ::: "memory");   // this wave's h at LLC
      __syncthreads();                                   // all 4 waves drained
      if (tid == 0)
        __hip_atomic_fetch_add(cnt + ((size_t)t * 8 + (wg >> 3)) * 16, 1u,
                               __ATOMIC_RELAXED, __HIP_MEMORY_SCOPE_AGENT);
    } else {
      float4 ho; ho.x = hv[0]; ho.y = hv[1]; ho.z = hv[2]; ho.w = hv[3];
      float4 co; co.x = cst[0]; co.y = cst[1]; co.z = cst[2]; co.w = cst[3];
      *reinterpret_cast<float4*>(out + (size_t)b * H_ + wg * 16 + jbase) = ho;
      *reinterpret_cast<float4*>(out + (size_t)(B_ * H_) + (size_t)b * H_ + wg * 16 + jbase) = co;
    }
  }

  if (t1 < T_){
    float4 cv; cv.x = cst[0]; cv.y = cst[1]; cv.z = cst[2]; cv.w = cst[3];
    *reinterpret_cast<float4*>(c_state + (size_t)b * H_ + wg * 16 + jbase) = cv;
  }
}

// ---------- launch ----------
extern "C" void kernel_launch(void* const* d_in, const int* in_sizes, int n_in,
                              void* d_out, int out_size, void* d_ws, size_t ws_size,
                              hipStream_t stream){
  const int*   src = (const int*)  d_in[0];
  const float* emb = (const float*)d_in[1];
  const float* Wx  = (const float*)d_in[2];
  const float* bx  = (const float*)d_in[3];
  const float* Wh  = (const float*)d_in[4];

  // ws: WxB(4MB) | embSeg(SEG*64KB) | xpSeg(SEG*512KB) | hring(SEG*128KB) | c_state(256KB) | cnt(512KB)
  const size_t FIXED  = 4194304 + 262144 + 524288;       // 4,980,736
  const size_t PERSEG = 65536 + 524288 + 131072;         // 720,896
  int SEG = 64;
  if (ws_size < FIXED + 64 * PERSEG){
    if      (ws_size >= FIXED + 16 * PERSEG) SEG = 16;
    else if (ws_size >= FIXED + 4  * PERSEG) SEG = 4;
    else                                     SEG = 2;
  }

  char*  ws      = (char*)d_ws;
  u16*   WxB     = (u16*)(ws);
  u16*   embSeg  = (u16*)(ws + 4194304);
  u16*   xpSeg   = (u16*)(ws + 4194304 + (size_t)SEG * 65536);
  u16*   hring   = (u16*)(ws + 4194304 + (size_t)SEG * 589824);
  float* c_state = (float*)(ws + 4194304 + (size_t)SEG * 720896);
  u32*   cnt     = (u32*) (ws + 4194304 + (size_t)SEG * 720896 + 262144);

  hipMemsetAsync(cnt, 0, (size_t)T_ * 8 * 64, stream);
  cvt_bf16<<<2048, 256, 0, stream>>>(Wx, WxB, G4_ * E_);

  const int nseg = T_ / SEG;
  for (int s = 0; s < nseg; ++s){
    const int t0   = s * SEG;
    const int rows = SEG * B_;
    emb_gather<<<rows / 2, 256, 0, stream>>>(src, emb, embSeg, t0);
    dim3 g(G4_ / 128, rows / 128);
    xproj_gemm<<<g, 256, 0, stream>>>(embSeg, WxB, bx, xpSeg);
    lstm_rec<<<NWG, 256, 0, stream>>>(Wh, xpSeg, hring, c_state, cnt,
                                      (float*)d_out, t0, t0 + SEG, SEG - 1);
  }
}